// Round 3
// baseline (462.479 us; speedup 1.0000x reference)
//
#include <hip/hip_runtime.h>

typedef unsigned short u16;
typedef unsigned int u32;
typedef unsigned long long u64;
typedef __attribute__((ext_vector_type(8))) short bf16x8;
typedef __attribute__((ext_vector_type(4))) float f32x4;

#define BATCH 128
#define NQL   384
#define NKL   384
#define NHEAD 8
#define HD    32
#define ADIM  256
#define QSCALE 0.17677669529663689f   // 1/sqrt(32)

__device__ __forceinline__ u16 f2bf(float f) {
    union { float f; u32 u; } v; v.f = f;
    u32 r = v.u + 0x7fffu + ((v.u >> 16) & 1u);
    return (u16)(r >> 16);
}
__device__ __forceinline__ float bf2f(u16 u) {
    union { u32 u; float f; } v; v.u = ((u32)u) << 16;
    return v.f;
}
__device__ __forceinline__ u32 pk(float a, float b) {
    return (u32)f2bf(a) | ((u32)f2bf(b) << 16);
}
// async global->LDS, 16 bytes per lane. LDS dest = wave-uniform base + lane*16,
// so pass per-lane lds ptr that is linear in lane id.
__device__ __forceinline__ void async_cp16(const void* g, void* l) {
    __builtin_amdgcn_global_load_lds(
        (const __attribute__((address_space(1))) u32*)g,
        (__attribute__((address_space(3))) u32*)(u32)(u64)l,
        16, 0, 0);
}

// ---------------------------------------------------------------------------
// Kernel 1: weights fp32 [K=256][N=256] -> bf16 [N][K]
// ---------------------------------------------------------------------------
__global__ __launch_bounds__(256) void prep_w_kernel(
    const float* __restrict__ qw, const float* __restrict__ kw,
    const float* __restrict__ vw, const float* __restrict__ gw,
    const float* __restrict__ ow, u16* __restrict__ wt)
{
    const float* src;
    switch (blockIdx.y) {
        case 0: src = qw; break;
        case 1: src = kw; break;
        case 2: src = vw; break;
        case 3: src = gw; break;
        default: src = ow; break;
    }
    u16* dst = wt + (size_t)blockIdx.y * 65536;
    int t = threadIdx.x;
    int n0 = blockIdx.x * 16;
    for (int i = 0; i < 16; i++) {
        int n = n0 + i;
        dst[n * 256 + t] = f2bf(src[t * 256 + n]);
    }
}

// ---------------------------------------------------------------------------
// Kernel 2: bias+nb -> bf16 pre-swizzled into MFMA C-frag layout
// out[b][qt][kt][lane][4] where lane=quad*16+col holds rows qt*16+quad*4+r,
// col kt*16+col.  grid (24 qt, 128 b) x 256
// ---------------------------------------------------------------------------
__global__ __launch_bounds__(256) void prep_bias_kernel(
    const float* __restrict__ bias, const float* __restrict__ nb,
    u16* __restrict__ bias_sw)
{
    const int qt = blockIdx.x, b = blockIdx.y;
    const int t = threadIdx.x;
    const int lane = t & 63, sub = t >> 6;
    const int col = lane & 15, quad = lane >> 4;
    const float* bb = bias + ((size_t)b * 384 + qt * 16) * 384;
    const float* nn = nb + (size_t)qt * 16 * 384;
    u16* outb = bias_sw + ((size_t)b * 24 + qt) * 24 * 256;
#pragma unroll
    for (int i = 0; i < 6; i++) {
        int kt = sub + i * 4;
        int c = kt * 16 + col;
        u16 v[4];
#pragma unroll
        for (int r = 0; r < 4; r++) {
            int q = quad * 4 + r;
            v[r] = f2bf(bb[(size_t)q * 384 + c] + nn[(size_t)q * 384 + c]);
        }
        *(uint2*)&outb[(size_t)kt * 256 + lane * 4] = *(uint2*)v;
    }
}

// ---------------------------------------------------------------------------
// Kernel 3: projection GEMM, one output matrix per block.
// C[128x256] = A[128x256 fp32] x W[256x256 bf16], block 256 thr / 4 waves,
// wave tile 64x128. W staged via global_load_lds; A converted in-register.
// grid (2 widx, 384 bm, 2 side)
// ---------------------------------------------------------------------------
__global__ __launch_bounds__(256, 2) void proj_kernel(
    const float* __restrict__ qd, const float* __restrict__ md,
    const u16* __restrict__ wt, const float* __restrict__ gb,
    u16* __restrict__ q_o, u16* __restrict__ k_o,
    u16* __restrict__ v_o, u16* __restrict__ g_o)
{
    const int widx = blockIdx.x;
    const int bm = blockIdx.y * 128;
    const int side = blockIdx.z;
    const float* A = side ? md : qd;
    const int wsel = side ? (widx ? 2 : 1) : (widx ? 3 : 0);
    const u16* W = wt + (size_t)wsel * 65536;
    u16* O = side ? (widx ? v_o : k_o) : (widx ? g_o : q_o);
    const int mode = side ? 0 : (widx ? 2 : 1);   // 1: q scale, 2: gate sigmoid

    const int tid = threadIdx.x;
    const int lane = tid & 63, wave = tid >> 6;
    const int col = lane & 15, quad = lane >> 4;
    const int mw = (wave & 1) * 64, nsl = (wave >> 1) * 128;

    __shared__ u16 Abf[128][32];   // 8 KB
    __shared__ u16 Wb[256][32];    // 16 KB

    f32x4 acc[4][8];
#pragma unroll
    for (int i = 0; i < 4; i++)
#pragma unroll
        for (int j = 0; j < 8; j++) acc[i][j] = (f32x4){0.f, 0.f, 0.f, 0.f};

    const int arow = tid >> 1, acb = (tid & 1) * 16;
    const float* asrc = A + (size_t)(bm + arow) * 256 + acb;
    const int wrow = tid >> 2, wcb = (tid & 3) * 8;

    for (int k0 = 0; k0 < 256; k0 += 32) {
        __syncthreads();
        // async W staging (4 x 16B per thread)
#pragma unroll
        for (int i = 0; i < 4; i++)
            async_cp16(W + (size_t)(i * 64 + wrow) * 256 + k0 + wcb,
                       (char*)Wb + i * 4096 + tid * 16);
        // A fp32 -> bf16 staging
        {
            float4 f0 = *(const float4*)(asrc + k0 + 0);
            float4 f1 = *(const float4*)(asrc + k0 + 4);
            float4 f2 = *(const float4*)(asrc + k0 + 8);
            float4 f3 = *(const float4*)(asrc + k0 + 12);
            uint4 u0 = make_uint4(pk(f0.x, f0.y), pk(f0.z, f0.w), pk(f1.x, f1.y), pk(f1.z, f1.w));
            uint4 u1 = make_uint4(pk(f2.x, f2.y), pk(f2.z, f2.w), pk(f3.x, f3.y), pk(f3.z, f3.w));
            *(uint4*)&Abf[arow][acb + 0] = u0;
            *(uint4*)&Abf[arow][acb + 8] = u1;
        }
        asm volatile("s_waitcnt vmcnt(0)" ::: "memory");
        __syncthreads();

        bf16x8 av[4], bv[8];
#pragma unroll
        for (int mt = 0; mt < 4; mt++)
            av[mt] = *(const bf16x8*)&Abf[mw + mt * 16 + col][quad * 8];
#pragma unroll
        for (int j = 0; j < 8; j++)
            bv[j] = *(const bf16x8*)&Wb[nsl + j * 16 + col][quad * 8];
#pragma unroll
        for (int mt = 0; mt < 4; mt++)
#pragma unroll
            for (int j = 0; j < 8; j++)
                acc[mt][j] = __builtin_amdgcn_mfma_f32_16x16x32_bf16(av[mt], bv[j], acc[mt][j], 0, 0, 0);
    }

#pragma unroll
    for (int j = 0; j < 8; j++) {
        int gn = nsl + j * 16 + col;
        float gbv = (mode == 2) ? gb[gn] : 0.f;
#pragma unroll
        for (int mt = 0; mt < 4; mt++) {
#pragma unroll
            for (int r = 0; r < 4; r++) {
                int gm = bm + mw + mt * 16 + quad * 4 + r;
                float v = acc[mt][j][r];
                if (mode == 1) v *= QSCALE;
                if (mode == 2) v = 1.f / (1.f + __expf(-(v + gbv)));
                O[(size_t)gm * 256 + gn] = f2bf(v);
            }
        }
    }
}

// ---------------------------------------------------------------------------
// Kernel 4: attention. One block per (b,h); 4 waves x 6 q-tiles of 16 rows.
// Bias comes pre-swizzled as MFMA C-operand (b64 load per tile, no staging).
// grid x = h*128 + b (same-b heads -> same XCD for L2 bias reuse)
// ---------------------------------------------------------------------------
__global__ __launch_bounds__(256) void attn_kernel(
    const u16* __restrict__ q_ws, const u16* __restrict__ k_ws,
    const u16* __restrict__ v_ws, const u16* __restrict__ g_ws,
    const u16* __restrict__ bias_sw, u16* __restrict__ wa_ws)
{
    const int h = blockIdx.x >> 7, bi = blockIdx.x & 127;
    const int tid = threadIdx.x;
    const int lane = tid & 63, wave = tid >> 6;
    const int col = lane & 15, quad = lane >> 4;

    __shared__ u16 Ks[384][32];                  // 24576 B
    __shared__ u16 Vt[32 * 384];                 // 24576 B, xor-swizzled [c][kv]
    __shared__ u16 Ps[4][16][72];                // 9216 B per-wave P scratch

    const u16* kg = k_ws + (size_t)bi * 384 * 256 + h * 32;
    const u16* vg = v_ws + (size_t)bi * 384 * 256 + h * 32;
    for (int f = tid * 8; f < 384 * 32; f += 256 * 8) {
        int kr = f >> 5, c = f & 31;
        *(uint4*)&Ks[kr][c] = *(const uint4*)&kg[kr * 256 + c];
    }
    for (int f = tid * 8; f < 384 * 32; f += 256 * 8) {
        int kv = f >> 5, c0 = f & 31;
        u16 tmp[8];
        *(uint4*)tmp = *(const uint4*)&vg[kv * 256 + c0];
        int kvg = kv >> 3, kvr = kv & 7;
#pragma unroll
        for (int j = 0; j < 8; j++) {
            int c = c0 + j;
            Vt[c * 384 + ((kvg ^ (c & 7)) << 3) + kvr] = tmp[j];
        }
    }
    __syncthreads();

    for (int qt = wave; qt < 24; qt += 4) {
        const int q0 = qt * 16;
        bf16x8 qf = *(const bf16x8*)(q_ws + ((size_t)(bi * 384 + q0 + col)) * 256 + h * 32 + quad * 8);
        const u16* bfr = bias_sw + ((size_t)(bi * 24 + qt)) * 24 * 256 + lane * 4;

        float S[24][4];
#pragma unroll
        for (int t = 0; t < 24; t++) {
            uint2 bw = *(const uint2*)(bfr + (size_t)t * 256);
            f32x4 ci;
            ci[0] = bf2f((u16)(bw.x & 0xffff));
            ci[1] = bf2f((u16)(bw.x >> 16));
            ci[2] = bf2f((u16)(bw.y & 0xffff));
            ci[3] = bf2f((u16)(bw.y >> 16));
            bf16x8 kf = *(const bf16x8*)&Ks[t * 16 + col][quad * 8];
            f32x4 a = __builtin_amdgcn_mfma_f32_16x16x32_bf16(qf, kf, ci, 0, 0, 0);
            S[t][0] = a[0]; S[t][1] = a[1]; S[t][2] = a[2]; S[t][3] = a[3];
        }

        // softmax over 384 cols
#pragma unroll
        for (int r = 0; r < 4; r++) {
            float m = S[0][r];
#pragma unroll
            for (int t = 1; t < 24; t++) m = fmaxf(m, S[t][r]);
#pragma unroll
            for (int o = 1; o < 16; o <<= 1) m = fmaxf(m, __shfl_xor(m, o));
            float s = 0.f;
#pragma unroll
            for (int t = 0; t < 24; t++) { float p = __expf(S[t][r] - m); S[t][r] = p; s += p; }
#pragma unroll
            for (int o = 1; o < 16; o <<= 1) s += __shfl_xor(s, o);
            float inv = 1.f / s;
#pragma unroll
            for (int t = 0; t < 24; t++) S[t][r] *= inv;
        }

        // O = P V via per-wave Ps round trip, swizzled Vt frags
        f32x4 o0 = (f32x4){0.f, 0.f, 0.f, 0.f};
        f32x4 o1 = (f32x4){0.f, 0.f, 0.f, 0.f};
#pragma unroll
        for (int g = 0; g < 6; g++) {
#pragma unroll
            for (int tt = 0; tt < 4; tt++) {
                int t = g * 4 + tt;
#pragma unroll
                for (int r = 0; r < 4; r++)
                    Ps[wave][quad * 4 + r][tt * 16 + col] = f2bf(S[t][r]);
            }
            asm volatile("s_waitcnt lgkmcnt(0)" ::: "memory");
            bf16x8 a0 = *(const bf16x8*)&Ps[wave][col][quad * 8];
            bf16x8 a1 = *(const bf16x8*)&Ps[wave][col][32 + quad * 8];
            const int e = col & 7;
            const int gg0 = g * 8 + quad;
            const int gg1 = gg0 + 4;
            bf16x8 b00 = *(const bf16x8*)&Vt[col * 384 + ((gg0 ^ e) << 3)];
            bf16x8 b01 = *(const bf16x8*)&Vt[col * 384 + ((gg1 ^ e) << 3)];
            bf16x8 b10 = *(const bf16x8*)&Vt[(col + 16) * 384 + ((gg0 ^ e) << 3)];
            bf16x8 b11 = *(const bf16x8*)&Vt[(col + 16) * 384 + ((gg1 ^ e) << 3)];
            o0 = __builtin_amdgcn_mfma_f32_16x16x32_bf16(a0, b00, o0, 0, 0, 0);
            o0 = __builtin_amdgcn_mfma_f32_16x16x32_bf16(a1, b01, o0, 0, 0, 0);
            o1 = __builtin_amdgcn_mfma_f32_16x16x32_bf16(a0, b10, o1, 0, 0, 0);
            o1 = __builtin_amdgcn_mfma_f32_16x16x32_bf16(a1, b11, o1, 0, 0, 0);
            asm volatile("s_waitcnt lgkmcnt(0)" ::: "memory");
        }

        // gate + store (wa aliases q_ws: q rows for this tile already consumed)
        const size_t rowbase = (size_t)bi * 384 + q0 + quad * 4;
#pragma unroll
        for (int r = 0; r < 4; r++) {
            size_t base = (rowbase + r) * 256 + h * 32;
            {
                size_t idx = base + col;
                wa_ws[idx] = f2bf(o0[r] * bf2f(g_ws[idx]));
            }
            {
                size_t idx = base + 16 + col;
                wa_ws[idx] = f2bf(o1[r] * bf2f(g_ws[idx]));
            }
        }
    }
}

// ---------------------------------------------------------------------------
// Kernel 5: output projection. out[128x256 fp32] = wa x output_w + ob
// All-bf16 inputs staged via global_load_lds. grid (384)
// ---------------------------------------------------------------------------
__global__ __launch_bounds__(256, 2) void outproj_kernel(
    const u16* __restrict__ wa, const u16* __restrict__ W,
    const float* __restrict__ ob, float* __restrict__ out)
{
    const int bm = blockIdx.x * 128;
    const int tid = threadIdx.x;
    const int lane = tid & 63, wave = tid >> 6;
    const int col = lane & 15, quad = lane >> 4;
    const int mw = (wave & 1) * 64, nsl = (wave >> 1) * 128;

    __shared__ u16 Abf[128][32];
    __shared__ u16 Wb[256][32];

    f32x4 acc[4][8];
#pragma unroll
    for (int i = 0; i < 4; i++)
#pragma unroll
        for (int j = 0; j < 8; j++) acc[i][j] = (f32x4){0.f, 0.f, 0.f, 0.f};

    const int wrow = tid >> 2, wcb = (tid & 3) * 8;

    for (int k0 = 0; k0 < 256; k0 += 32) {
        __syncthreads();
#pragma unroll
        for (int i = 0; i < 2; i++)
            async_cp16(wa + (size_t)(bm + i * 64 + wrow) * 256 + k0 + wcb,
                       (char*)Abf + i * 4096 + tid * 16);
#pragma unroll
        for (int i = 0; i < 4; i++)
            async_cp16(W + (size_t)(i * 64 + wrow) * 256 + k0 + wcb,
                       (char*)Wb + i * 4096 + tid * 16);
        asm volatile("s_waitcnt vmcnt(0)" ::: "memory");
        __syncthreads();

        bf16x8 av[4], bv[8];
#pragma unroll
        for (int mt = 0; mt < 4; mt++)
            av[mt] = *(const bf16x8*)&Abf[mw + mt * 16 + col][quad * 8];
#pragma unroll
        for (int j = 0; j < 8; j++)
            bv[j] = *(const bf16x8*)&Wb[nsl + j * 16 + col][quad * 8];
#pragma unroll
        for (int mt = 0; mt < 4; mt++)
#pragma unroll
            for (int j = 0; j < 8; j++)
                acc[mt][j] = __builtin_amdgcn_mfma_f32_16x16x32_bf16(av[mt], bv[j], acc[mt][j], 0, 0, 0);
    }

#pragma unroll
    for (int j = 0; j < 8; j++) {
        int gn = nsl + j * 16 + col;
        float obv = ob[gn];
#pragma unroll
        for (int mt = 0; mt < 4; mt++) {
#pragma unroll
            for (int r = 0; r < 4; r++) {
                int gm = bm + mw + mt * 16 + quad * 4 + r;
                out[(size_t)gm * 256 + gn] = acc[mt][j][r] + obv;
            }
        }
    }
}

// ---------------------------------------------------------------------------
extern "C" void kernel_launch(void* const* d_in, const int* in_sizes, int n_in,
                              void* d_out, int out_size, void* d_ws, size_t ws_size,
                              hipStream_t stream)
{
    const float* q_data = (const float*)d_in[0];
    const float* m_data = (const float*)d_in[1];
    const float* bias   = (const float*)d_in[2];
    const float* nb     = (const float*)d_in[3];
    const float* qw     = (const float*)d_in[4];
    const float* kw     = (const float*)d_in[5];
    const float* vw     = (const float*)d_in[6];
    const float* gw     = (const float*)d_in[7];
    const float* gb     = (const float*)d_in[8];
    const float* ow     = (const float*)d_in[9];
    const float* ob     = (const float*)d_in[10];
    float* out = (float*)d_out;

    char* ws = (char*)d_ws;
    u16* wt = (u16*)ws;                               // 640 KB
    const size_t PROJ = (size_t)BATCH * NQL * 256;    // 12,582,912 elems (24 MB bf16)
    u16* q_ws  = (u16*)(ws + (1 << 20));
    u16* k_ws  = q_ws + PROJ;
    u16* v_ws  = k_ws + PROJ;
    u16* g_ws  = v_ws + PROJ;
    u16* bias_sw = g_ws + PROJ;                       // 128*24*24*256 = 18,874,368 elems (36 MB)
    u16* wa_ws = q_ws;                                // aliased: attn consumes q before writing wa

    prep_w_kernel<<<dim3(16, 5), 256, 0, stream>>>(qw, kw, vw, gw, ow, wt);
    prep_bias_kernel<<<dim3(24, 128), 256, 0, stream>>>(bias, nb, bias_sw);
    proj_kernel<<<dim3(2, 384, 2), 256, 0, stream>>>(q_data, m_data, wt, gb,
                                                     q_ws, k_ws, v_ws, g_ws);
    attn_kernel<<<dim3(1024), 256, 0, stream>>>(q_ws, k_ws, v_ws, g_ws,
                                                bias_sw, wa_ws);
    outproj_kernel<<<dim3(384), 256, 0, stream>>>(wa_ws, wt + 4 * 65536, ob, out);
}